// Round 1
// 1647.788 us; speedup vs baseline: 1.4780x; 1.4780x over previous
//
#include <hip/hip_runtime.h>
#include <cstdint>
#include <cstddef>

// ---------- helpers ----------
__device__ __forceinline__ unsigned short f2h(float f) {
    union { _Float16 h; unsigned short u; } c; c.h = (_Float16)f; return c.u;
}
__device__ __forceinline__ float h2f(unsigned short u) {
    union { unsigned short u; _Float16 h; } c; c.u = u; return (float)c.h;
}

typedef _Float16 f16x8 __attribute__((ext_vector_type(8)));
typedef float    f32x4 __attribute__((ext_vector_type(4)));

// async global->LDS, 16B per lane. HW: LDS dest = wave-uniform base + lane*16.
__device__ __forceinline__ void gload16(const void* g, void* l) {
    __builtin_amdgcn_global_load_lds(
        (const __attribute__((address_space(1))) unsigned int*)g,
        (__attribute__((address_space(3))) unsigned int*)l,
        16, 0, 0);
}

// raw barrier / counted waits (no vmcnt(0) drain at barriers — T3/T4)
#define BAR()   asm volatile("s_barrier" ::: "memory")
#define LGKM0() asm volatile("s_waitcnt lgkmcnt(0)" ::: "memory")
#define LGKM8() asm volatile("s_waitcnt lgkmcnt(8)" ::: "memory")
#define VMW(N)  asm volatile("s_waitcnt vmcnt(" #N ")" ::: "memory")

// ---------- f32 -> f16 elementwise (input_tensor), 8 elems/thread ----------
__global__ __launch_bounds__(256) void cvt_f32_f16(const float* __restrict__ in,
                                                   _Float16* __restrict__ out) {
    const size_t i = ((size_t)blockIdx.x * 256 + threadIdx.x) * 8;
    const float4 a = *(const float4*)(in + i);
    const float4 b = *(const float4*)(in + i + 4);
    f16x8 v;
    v[0] = (_Float16)a.x; v[1] = (_Float16)a.y; v[2] = (_Float16)a.z; v[3] = (_Float16)a.w;
    v[4] = (_Float16)b.x; v[5] = (_Float16)b.y; v[6] = (_Float16)b.z; v[7] = (_Float16)b.w;
    *(f16x8*)(out + i) = v;
}

// ---------- transpose + f32->f16: in[R][C] (f32) -> out[C][R] (f16) ----------
__global__ __launch_bounds__(256) void transpose_cvt64(const float* __restrict__ in,
                                                       _Float16* __restrict__ out,
                                                       int R, int C) {
    __shared__ __align__(16) _Float16 tile[64][68];
    const int t = threadIdx.x;
    const int r0 = blockIdx.y << 6, c0 = blockIdx.x << 6;
#pragma unroll
    for (int p = 0; p < 4; ++p) {
        const int id  = p * 256 + t;
        const int row = id >> 4;
        const int cg  = (id & 15) << 2;
        const float4 v = *(const float4*)(in + (size_t)(r0 + row) * C + (c0 + cg));
        tile[cg + 0][row] = (_Float16)v.x;
        tile[cg + 1][row] = (_Float16)v.y;
        tile[cg + 2][row] = (_Float16)v.z;
        tile[cg + 3][row] = (_Float16)v.w;
    }
    __syncthreads();
#pragma unroll
    for (int p = 0; p < 4; ++p) {
        const int id   = p * 256 + t;
        const int crow = id >> 4;
        const int rg   = (id & 15) << 2;
        ushort4 v;
        v.x = ((const unsigned short*)&tile[crow][rg])[0];
        v.y = ((const unsigned short*)&tile[crow][rg])[1];
        v.z = ((const unsigned short*)&tile[crow][rg])[2];
        v.w = ((const unsigned short*)&tile[crow][rg])[3];
        *(ushort4*)((unsigned short*)out + (size_t)(c0 + crow) * R + (r0 + rg)) = v;
    }
}

// ---------- 16-MFMA cluster: one C-quadrant (4 m-frags x 2 n-frags x 2 ks) ----------
__device__ __forceinline__ void mfma16(f32x4 (&acc)[4][2],
                                       const f16x8 (&a)[4][2],
                                       const f16x8 (&b)[2][2]) {
#pragma unroll
    for (int i = 0; i < 4; ++i)
#pragma unroll
        for (int j = 0; j < 2; ++j)
#pragma unroll
            for (int ks = 0; ks < 2; ++ks)
                acc[i][j] = __builtin_amdgcn_mfma_f32_16x16x32_f16(a[i][ks], b[j][ks], acc[i][j], 0, 0, 0);
}

// ---------- GEMM: C = A[MxK] * BT[NxK]^T — 256x256 tile, BK=64, 8-phase ----------
// 512 threads = 8 waves (2x4). Per-wave output 128x64. LDS = 4 half-slots per
// operand (16KB each) = 128 KiB. Staging runs 3 half-tiles ahead; vmcnt(6) only
// once per K-tile (counted, never 0 in steady state). LDS XOR-swizzle
// (slot ^= row&7) applied as pre-swizzled global source + swizzled ds_read
// (linear LDS dest, as global_load_lds requires).
// Per K-tile phases = block-C quadrants:
//   ph0 (qm0,qn0): read af(A-h0) 8x + bf0(B-h0) 4x | stage A-h1(t+1)
//   ph1 (qm0,qn1): read bf1(B-h1) 4x               | stage A-h0(t+2)
//   ph2 (qm1,qn0): read af(A-h1) 8x                | stage B-h0(t+2)
//   ph3 (qm1,qn1): no reads                        | stage B-h1(t+2), vmcnt
// EPI as before: 0=f16(v+b), 1=f16(relu), 2=RMW weighted relu, 3=f32 out.
template <int EPI>
__global__ __launch_bounds__(512, 2) void gemm256(
    const _Float16* __restrict__ A,          // M x K (f16)
    const _Float16* __restrict__ BT,         // N x K (f16)
    const float* __restrict__ bias,          // f32 [N]
    unsigned short* __restrict__ o16,        // f16 out
    float* __restrict__ of32,                // f32 out
    const float* __restrict__ ew,            // f32 [M][8]
    int M, int N, int K, int expert, int first)
{
    __shared__ __align__(16) _Float16 As[4 * 8192];   // 4 half-slots x 128x64
    __shared__ __align__(16) _Float16 Bs[4 * 8192];

    const int tid  = threadIdx.x;
    const int lane = tid & 63;
    const int wave = tid >> 6;
    const int quad = lane >> 4, r16 = lane & 15;
    const int wm = wave >> 2, wn = wave & 3;          // 2 x 4 wave grid

    // T1: XCD-contiguous block swizzle (grid size divisible by 8 in all uses)
    const int gx  = gridDim.x;
    const int nwg = gx * gridDim.y;
    int wg = blockIdx.y * gx + blockIdx.x;
    const int qch = nwg >> 3;
    wg = (wg & 7) * qch + (wg >> 3);
    const int m0 = (wg / gx) << 8;
    const int n0 = (wg % gx) << 8;

    const int nkt = K >> 6;                           // K-tiles of 64 (>=16 here)

    // ---- staging addresses (pre-swizzled source; linear LDS dest) ----
    // chunk c = issue*512 + tid ; row = c>>3 (0..127), slot16B = c&7
    // source k-slot = (c&7) ^ (row&7)  (row&7 invariant under issue since +64)
    const int srow  = tid >> 3;                       // 0..63
    const int sslot = ((tid & 7) ^ (srow & 7)) << 3;  // f16 col offset
    const _Float16* gA = A  + (size_t)(m0 + srow) * K + sslot;
    const _Float16* gB = BT + (size_t)(n0 + srow) * K + sslot;
    _Float16* lA = As + tid * 8;                      // chunk -> lds + c*16B
    _Float16* lB = Bs + tid * 8;
    const size_t rstep = (size_t)64 * K;              // second chunk (+64 rows)
    const size_t hstep = (size_t)128 * K;             // half offset

#define STAGE(gp, lp) do { gload16((gp), (lp)); gload16((gp) + rstep, (lp) + 4096); } while (0)

    // ---- ds_read addressing (swizzled) ----
    const int s7   = r16 & 7;
    const int swk0 = (quad ^ s7) << 3;                // ks=0: f16 offset in 64-f16 row
    const int swk1 = ((quad + 4) ^ s7) << 3;          // ks=1
    const int rA   = (wm << 6) + r16;                 // A row base within half (0..127)
    const int rB   = (wn << 5) + r16;                 // B row base within half (0..127)

    f32x4 acc[2][2][4][2];
#pragma unroll
    for (int qm = 0; qm < 2; ++qm)
#pragma unroll
        for (int qn = 0; qn < 2; ++qn)
#pragma unroll
            for (int i = 0; i < 4; ++i)
#pragma unroll
                for (int j = 0; j < 2; ++j)
#pragma unroll
                    for (int r = 0; r < 4; ++r) acc[qm][qn][i][j][r] = 0.f;

    f16x8 af[4][2], bf0[2][2], bf1[2][2];

    // ---- prologue: tile0 {Ah0,Bh0,Bh1,Ah1} -> slots {A0,B0,B1,A1};
    //                tile1 {Ah0,Bh0,Bh1}     -> slots {A2,B2,B3}  (Ah1(1) at t0.ph0)
    STAGE(gA,             lA);
    STAGE(gB,             lB);
    STAGE(gB + hstep,     lB + 8192);
    STAGE(gA + hstep,     lA + 8192);
    VMW(4);
    STAGE(gA + 64,         lA + 16384);
    STAGE(gB + 64,         lB + 16384);
    STAGE(gB + 64 + hstep, lB + 24576);
    VMW(6);                 // tile0 fully landed; tile1 halves 0..2 in flight
    BAR();

    for (int t = 0; t < nkt; ++t) {
        const int cur = (t & 1) << 1;                 // slot of h0 for tile t
        const _Float16* Abase = As + cur * 8192;
        const _Float16* Bbase = Bs + cur * 8192;
        const int kcol = t << 6;
        const int nslot = (((t + 1) & 1) << 1) + 1;   // A-h1 slot of tile t+1

        // ---------------- phase 0 : quadrant (0,0) ----------------
#pragma unroll
        for (int i = 0; i < 4; ++i) {
            af[i][0] = *(const f16x8*)(Abase + (rA + i * 16) * 64 + swk0);
            af[i][1] = *(const f16x8*)(Abase + (rA + i * 16) * 64 + swk1);
        }
#pragma unroll
        for (int j = 0; j < 2; ++j) {
            bf0[j][0] = *(const f16x8*)(Bbase + (rB + j * 16) * 64 + swk0);
            bf0[j][1] = *(const f16x8*)(Bbase + (rB + j * 16) * 64 + swk1);
        }
        if (t + 1 < nkt) STAGE(gA + (kcol + 64) + hstep, lA + nslot * 8192);
        LGKM8();
        BAR();
        LGKM0();
        __builtin_amdgcn_s_setprio(1);
        mfma16(acc[0][0], af, bf0);
        __builtin_amdgcn_s_setprio(0);
        BAR();

        // ---------------- phase 1 : quadrant (0,1) ----------------
#pragma unroll
        for (int j = 0; j < 2; ++j) {
            bf1[j][0] = *(const f16x8*)(Bbase + 8192 + (rB + j * 16) * 64 + swk0);
            bf1[j][1] = *(const f16x8*)(Bbase + 8192 + (rB + j * 16) * 64 + swk1);
        }
        if (t + 2 < nkt) STAGE(gA + (kcol + 128), lA + cur * 8192);
        BAR();
        LGKM0();
        __builtin_amdgcn_s_setprio(1);
        mfma16(acc[0][1], af, bf1);
        __builtin_amdgcn_s_setprio(0);
        BAR();

        // ---------------- phase 2 : quadrant (1,0) ----------------
#pragma unroll
        for (int i = 0; i < 4; ++i) {
            af[i][0] = *(const f16x8*)(Abase + 8192 + (rA + i * 16) * 64 + swk0);
            af[i][1] = *(const f16x8*)(Abase + 8192 + (rA + i * 16) * 64 + swk1);
        }
        if (t + 2 < nkt) STAGE(gB + (kcol + 128), lB + cur * 8192);
        BAR();
        LGKM0();
        __builtin_amdgcn_s_setprio(1);
        mfma16(acc[1][0], af, bf0);
        __builtin_amdgcn_s_setprio(0);
        BAR();

        // ---------------- phase 3 : quadrant (1,1) ----------------
        if (t + 2 < nkt) {
            STAGE(gB + (kcol + 128) + hstep, lB + cur * 8192 + 8192);
            VMW(6);           // tile t+1 fully landed; t+2 halves 0..2 in flight
        } else if (t + 1 < nkt) {
            VMW(0);           // epilogue drain: last tile must be complete
        }
        BAR();
        LGKM0();
        __builtin_amdgcn_s_setprio(1);
        mfma16(acc[1][1], af, bf1);
        __builtin_amdgcn_s_setprio(0);
        BAR();
    }
#undef STAGE

    // ---- epilogue: m = m0 + qm*128 + wm*64 + i*16 + quad*4 + r
    //               n = n0 + qn*128 + wn*32 + j*16 + r16
    float bj[2][2];
#pragma unroll
    for (int qn = 0; qn < 2; ++qn)
#pragma unroll
        for (int j = 0; j < 2; ++j)
            bj[qn][j] = bias[n0 + qn * 128 + (wn << 5) + j * 16 + r16];

#pragma unroll
    for (int qm = 0; qm < 2; ++qm)
#pragma unroll
    for (int i = 0; i < 4; ++i) {
        const int mb = m0 + qm * 128 + (wm << 6) + i * 16 + (quad << 2);
#pragma unroll
        for (int r = 0; r < 4; ++r) {
            const int m = mb + r;
            float w = 0.f;
            if (EPI == 2) w = ew[(size_t)m * 8 + expert];
#pragma unroll
            for (int qn = 0; qn < 2; ++qn)
#pragma unroll
            for (int j = 0; j < 2; ++j) {
                const int n = n0 + qn * 128 + (wn << 5) + j * 16 + r16;
                const size_t idx = (size_t)m * N + n;
                float v = acc[qm][qn][i][j][r] + bj[qn][j];
                if (EPI == 0) {
                    o16[idx] = f2h(v);
                } else if (EPI == 1) {
                    o16[idx] = f2h(fmaxf(v, 0.f));
                } else if (EPI == 2) {
                    float tv = w * fmaxf(v, 0.f);
                    if (!first) tv += h2f(o16[idx]);
                    o16[idx] = f2h(tv);
                } else {
                    of32[idx] = v;
                }
            }
        }
    }
}

// ---------- LayerNorm over D=1024, fp32 in -> fp32 out ----------
__global__ __launch_bounds__(256) void ln_rows(const float* __restrict__ x,
                                               const float* __restrict__ gamma,
                                               const float* __restrict__ beta,
                                               float* __restrict__ out) {
    const int row = blockIdx.x;
    const int t = threadIdx.x;
    const float4 v = *(const float4*)(x + (size_t)row * 1024 + t * 4);
    float s  = v.x + v.y + v.z + v.w;
    float ss = v.x * v.x + v.y * v.y + v.z * v.z + v.w * v.w;
#pragma unroll
    for (int off = 32; off > 0; off >>= 1) {
        s  += __shfl_down(s,  off, 64);
        ss += __shfl_down(ss, off, 64);
    }
    __shared__ float red[8];
    const int lane = t & 63, wv = t >> 6;
    if (lane == 0) { red[wv] = s; red[4 + wv] = ss; }
    __syncthreads();
    const float S  = red[0] + red[1] + red[2] + red[3];
    const float SS = red[4] + red[5] + red[6] + red[7];
    const float mean = S * (1.f / 1024.f);
    const float var  = SS * (1.f / 1024.f) - mean * mean;
    const float rstd = rsqrtf(var + 1e-5f);
    const float4 g4 = *(const float4*)(gamma + t * 4);
    const float4 b4 = *(const float4*)(beta + t * 4);
    float4 o;
    o.x = (v.x - mean) * rstd * g4.x + b4.x;
    o.y = (v.y - mean) * rstd * g4.y + b4.y;
    o.z = (v.z - mean) * rstd * g4.z + b4.z;
    o.w = (v.w - mean) * rstd * g4.w + b4.w;
    *(float4*)(out + (size_t)row * 1024 + t * 4) = o;
}

// ---------- host ----------
extern "C" void kernel_launch(void* const* d_in, const int* in_sizes, int n_in,
                              void* d_out, int out_size, void* d_ws, size_t ws_size,
                              hipStream_t stream) {
    const int M = 8192, D = 1024, H = 2048, E = 8;

    const float* X  = (const float*)d_in[0];
    const float* EW = (const float*)d_in[1];
    const float* Wi = (const float*)d_in[2];
    const float* bi = (const float*)d_in[3];
    const float* W1 = (const float*)d_in[4];
    const float* b1 = (const float*)d_in[5];
    const float* W2 = (const float*)d_in[6];
    const float* b2 = (const float*)d_in[7];
    const float* Wo = (const float*)d_in[8];
    const float* bo = (const float*)d_in[9];
    const float* gm = (const float*)d_in[10];
    const float* bt = (const float*)d_in[11];

    char* wsp = (char*)d_ws;
    size_t off = 0;
    auto alloc = [&](size_t bytes) { char* p = wsp + off; off += bytes; return p; };
    _Float16* WiT  = (_Float16*)alloc((size_t)H * D * 2);
    _Float16* WoT  = (_Float16*)alloc((size_t)D * H * 2);
    _Float16* W1Te = (_Float16*)alloc((size_t)H * H * 2);
    _Float16* W2Te = (_Float16*)alloc((size_t)H * H * 2);
    _Float16* Xh   = (_Float16*)alloc((size_t)M * D * 2);
    _Float16* h    = (_Float16*)alloc((size_t)M * H * 2);
    _Float16* e1   = (_Float16*)alloc((size_t)M * H * 2);
    _Float16* cmb  = (_Float16*)alloc((size_t)M * H * 2);
    float* preLN   = (float*)h;                      // h dead after last expert L1

    dim3 blk(256), gblk(512);

    cvt_f32_f16<<<(M * D) / 2048, blk, 0, stream>>>(X, Xh);
    transpose_cvt64<<<dim3(H / 64, D / 64), blk, 0, stream>>>(Wi, WiT, D, H);
    transpose_cvt64<<<dim3(D / 64, H / 64), blk, 0, stream>>>(Wo, WoT, H, D);

    // GEMM1: h = X*Wi + bi     (M x 2048, K=1024) -> 256 blocks
    gemm256<0><<<dim3(H / 256, M / 256), gblk, 0, stream>>>(
        Xh, WiT, bi, (unsigned short*)h, nullptr, nullptr, M, H, D, 0, 0);

    for (int e = 0; e < E; ++e) {
        transpose_cvt64<<<dim3(H / 64, H / 64), blk, 0, stream>>>(
            W1 + (size_t)e * H * H, W1Te, H, H);
        gemm256<1><<<dim3(H / 256, M / 256), gblk, 0, stream>>>(
            h, W1Te, b1 + (size_t)e * H, (unsigned short*)e1, nullptr, nullptr, M, H, H, 0, 0);
        transpose_cvt64<<<dim3(H / 64, H / 64), blk, 0, stream>>>(
            W2 + (size_t)e * H * H, W2Te, H, H);
        gemm256<2><<<dim3(H / 256, M / 256), gblk, 0, stream>>>(
            e1, W2Te, b2 + (size_t)e * H, (unsigned short*)cmb, nullptr, EW, M, H, H, e, e == 0);
    }

    // GEMM4: preLN = combined*Wo + bo (M x 1024, K=2048) -> 128 blocks
    gemm256<3><<<dim3(D / 256, M / 256), gblk, 0, stream>>>(
        cmb, WoT, bo, nullptr, preLN, nullptr, M, D, H, 0, 0);

    ln_rows<<<M, blk, 0, stream>>>(preLN, gm, bt, (float*)d_out);
}